// Round 19
// baseline (189.215 us; speedup 1.0000x reference)
//
#include <hip/hip_runtime.h>
#include <hip/hip_fp16.h>

#define NN  40000
#define NE  640000
#define ND  128
#define ED  64
#define NH  8
#define DK  16
#define NWT 912   // 384 (q|k|v) + 512 (G composed) + 16 (SB rows, 8 used)

#define SCAN_NBLK 157   // ceil(40000/256)
#define PREP_NBLK 524   // ceil((NWT*ND + ND*ND + NWT)/256)
#define GEMM1_NBLK 625  // NN/64

typedef _Float16 f16x8 __attribute__((ext_vector_type(8)));
typedef float    f32x4 __attribute__((ext_vector_type(4)));

// ---- prep (WT/woT/bias compose) + hist, merged into one launch ----
__global__ __launch_bounds__(256) void k_prep_hist(const float* __restrict__ wq,
                                                   const float* __restrict__ bq,
                                                   const float* __restrict__ wk,
                                                   const float* __restrict__ bk,
                                                   const float* __restrict__ wv,
                                                   const float* __restrict__ bv,
                                                   const float* __restrict__ we,
                                                   const float* __restrict__ be,
                                                   const float* __restrict__ wo,
                                                   const int* __restrict__ ei,
                                                   __half* __restrict__ WT,
                                                   __half* __restrict__ woT,
                                                   float* __restrict__ bias_all,
                                                   int* __restrict__ hist) {
  if (blockIdx.x >= PREP_NBLK) {
    const int e = (blockIdx.x - PREP_NBLK) * 256 + threadIdx.x;
    if (e < NE) atomicAdd(&hist[ei[e]], 1);
    return;
  }
  int idx = blockIdx.x * 256 + threadIdx.x;
  if (idx < NWT * ND) {
    const int n = idx >> 7, k = idx & 127;
    float v;
    if (n < 128)      v = wq[k * ND + n];
    else if (n < 256) v = wk[k * ND + (n - 128)];
    else if (n < 384) v = wv[k * ND + (n - 256)];
    else if (n < 896) {
      const int col = n - 384, h = col >> 6, j = col & 63;
      const float4* a = (const float4*)(wq + (size_t)k * ND + h * DK);
      const float4* b = (const float4*)(we + (size_t)j * ND + h * DK);
      float s = 0.f;
#pragma unroll
      for (int i = 0; i < 4; ++i) {
        float4 av = a[i], bv4 = b[i];
        s = fmaf(av.x, bv4.x, s); s = fmaf(av.y, bv4.y, s);
        s = fmaf(av.z, bv4.z, s); s = fmaf(av.w, bv4.w, s);
      }
      v = 0.25f * s;
    } else if (n < 904) {
      const int h = n - 896;
      const float4* a = (const float4*)(wq + (size_t)k * ND + h * DK);
      const float4* b = (const float4*)(be + h * DK);
      float s = 0.f;
#pragma unroll
      for (int i = 0; i < 4; ++i) {
        float4 av = a[i], bv4 = b[i];
        s = fmaf(av.x, bv4.x, s); s = fmaf(av.y, bv4.y, s);
        s = fmaf(av.z, bv4.z, s); s = fmaf(av.w, bv4.w, s);
      }
      v = 0.25f * s;
    } else v = 0.f;
    WT[idx] = __float2half_rn(v);
    return;
  }
  idx -= NWT * ND;
  if (idx < ND * ND) {
    const int n = idx >> 7, k = idx & 127;
    woT[idx] = __float2half_rn(wo[k * ND + n]);
    return;
  }
  idx -= ND * ND;
  if (idx < NWT) {
    float v;
    if (idx < 128)      v = bq[idx];
    else if (idx < 256) v = bk[idx - 128];
    else if (idx < 384) v = bv[idx - 256];
    else if (idx < 896) {
      const int col = idx - 384, h = col >> 6, j = col & 63;
      const float4* a = (const float4*)(bq + h * DK);
      const float4* b = (const float4*)(we + (size_t)j * ND + h * DK);
      float s = 0.f;
#pragma unroll
      for (int i = 0; i < 4; ++i) {
        float4 av = a[i], bv4 = b[i];
        s = fmaf(av.x, bv4.x, s); s = fmaf(av.y, bv4.y, s);
        s = fmaf(av.z, bv4.z, s); s = fmaf(av.w, bv4.w, s);
      }
      v = 0.25f * s;
    } else if (idx < 904) {
      const int h = idx - 896;
      const float4* a = (const float4*)(bq + h * DK);
      const float4* b = (const float4*)(be + h * DK);
      float s = 0.f;
#pragma unroll
      for (int i = 0; i < 4; ++i) {
        float4 av = a[i], bv4 = b[i];
        s = fmaf(av.x, bv4.x, s); s = fmaf(av.y, bv4.y, s);
        s = fmaf(av.z, bv4.z, s); s = fmaf(av.w, bv4.w, s);
      }
      v = 0.25f * s;
    } else v = 0.f;
    bias_all[idx] = v;
  }
}

// ---- single-kernel CSR scan: local scan + decoupled lookback --------------
// pub[b] holds block-b total + 1 (0 = not published). 157 blocks all resident
// -> spin is deadlock-free. Value-as-flag: no separate fence needed.
__global__ __launch_bounds__(256) void k_scan_fused(const int* __restrict__ hist,
                                                    int* __restrict__ off,
                                                    int* __restrict__ cursor,
                                                    int* __restrict__ pub) {
  __shared__ int sh[256];
  const int tid = threadIdx.x;
  const int b = blockIdx.x;
  const int idx = b * 256 + tid;
  const int v = (idx < NN) ? hist[idx] : 0;
  sh[tid] = v;
  __syncthreads();
#pragma unroll
  for (int d = 1; d < 256; d <<= 1) {
    int t = (tid >= d) ? sh[tid - d] : 0;
    __syncthreads();
    sh[tid] += t;
    __syncthreads();
  }
  const int incl = sh[tid];
  const int total = sh[255];

  if (tid == 0) atomicExch(&pub[b], total + 1);

  int contrib = 0;
  if (tid < b) {
    int vv;
    do { vv = atomicAdd(&pub[tid], 0); } while (vv == 0);
    contrib = vv - 1;
  }
  __syncthreads();
  sh[tid] = contrib;
  __syncthreads();
#pragma unroll
  for (int d = 128; d > 0; d >>= 1) {
    if (tid < d) sh[tid] += sh[tid + d];
    __syncthreads();
  }
  const int excl = incl - v + sh[0];
  if (idx < NN) {
    off[idx] = excl;
    cursor[idx] = excl;
  }
  if (b == 0 && tid == 0) off[NN] = NE;
}

// ---- fused: MFMA GEMM 1 (blocks 0..624) + CSR scatter (blocks 625..) ----
__global__ __launch_bounds__(256) void k_gemm1_scatter(const float* __restrict__ x,
                                                       const __half* __restrict__ WT,
                                                       const float* __restrict__ bias_all,
                                                       const int* __restrict__ ei,
                                                       int* __restrict__ cursor,
                                                       int2* __restrict__ pair,
                                                       __half* __restrict__ qh,
                                                       __half* __restrict__ K16,
                                                       __half* __restrict__ V16,
                                                       __half* __restrict__ G16,
                                                       float* __restrict__ SB) {
  __shared__ _Float16 bs[4][16][132];

  if (blockIdx.x >= GEMM1_NBLK) {
    const int e = (blockIdx.x - GEMM1_NBLK) * 256 + threadIdx.x;
    if (e < NE) {
      const int row = ei[e];
      const int col = ei[NE + e];
      const int pos = atomicAdd(&cursor[row], 1);
      pair[pos] = make_int2(col, e);
    }
    return;
  }

  const int wave = threadIdx.x >> 6;
  const int l    = threadIdx.x & 63;
  const int row  = l & 15;
  const int kq   = l >> 4;
  const int r0   = blockIdx.x * 64 + wave * 16;

  f16x8 a[4];
#pragma unroll
  for (int s = 0; s < 4; ++s) {
    const float4* ap = (const float4*)(x + (size_t)(r0 + row) * ND + s * 32 + kq * 8);
    const float4 f0 = ap[0], f1 = ap[1];
    f16x8 t;
    t[0] = (_Float16)f0.x; t[1] = (_Float16)f0.y; t[2] = (_Float16)f0.z; t[3] = (_Float16)f0.w;
    t[4] = (_Float16)f1.x; t[5] = (_Float16)f1.y; t[6] = (_Float16)f1.z; t[7] = (_Float16)f1.w;
    a[s] = t;
  }

  const int rb = r0 + kq * 4;

  for (int nc = 0; nc < 56; nc += 4) {
    __syncthreads();
    {
      const __half* src = WT + (size_t)((nc + wave) * 16 + row) * ND;
      _Float16* dst = &bs[wave][row][0];
#pragma unroll
      for (int ch = 0; ch < 4; ++ch) {
        const int o = (kq + ch * 4) * 8;
        *(f16x8*)(dst + o) = *(const f16x8*)(src + o);
      }
    }
    __syncthreads();
#pragma unroll
    for (int t = 0; t < 4; ++t) {
      const int nt = nc + t;
      f32x4 c = {0.f, 0.f, 0.f, 0.f};
#pragma unroll
      for (int s = 0; s < 4; ++s) {
        const f16x8 b = *(const f16x8*)&bs[t][row][s * 32 + kq * 8];
        c = __builtin_amdgcn_mfma_f32_16x16x32_f16(a[s], b, c, 0, 0, 0);
      }
      const int col = nt * 16 + row;
      const float bb = bias_all[col];
      if (nt < 24) {
        __half* dst = (nt < 8) ? (qh + col) : (nt < 16) ? (K16 + (col - 128)) : (V16 + (col - 256));
#pragma unroll
        for (int i = 0; i < 4; ++i)
          dst[(size_t)(rb + i) * ND] = __float2half_rn(c[i] + bb);
      } else {
        const int gcol = col - 384;
#pragma unroll
        for (int i = 0; i < 4; ++i)
          G16[(size_t)(rb + i) * 512 + gcol] = __float2half_rn(c[i] + bb);
      }
    }
  }

  {
    f32x4 c = {0.f, 0.f, 0.f, 0.f};
#pragma unroll
    for (int s = 0; s < 4; ++s) {
      const f16x8 b = *(const f16x8*)(WT + (size_t)(896 + row) * ND + s * 32 + kq * 8);
      c = __builtin_amdgcn_mfma_f32_16x16x32_f16(a[s], b, c, 0, 0, 0);
    }
    if (row < 8) {
      const float bb = bias_all[896 + row];
#pragma unroll
      for (int i = 0; i < 4; ++i)
        SB[(size_t)(rb + i) * NH + row] = c[i] + bb;
    }
  }
}

// ---- MFMA GEMM 2: mh(f16) @ woT^T + bo -> out(f32); woT fully LDS-staged ----
__global__ __launch_bounds__(256) void k_gemm2(const __half* __restrict__ mh,
                                               const __half* __restrict__ woT,
                                               const float* __restrict__ bo,
                                               float* __restrict__ out) {
  __shared__ _Float16 ws[128][132];
  const int tid  = threadIdx.x;
  const int wave = tid >> 6;
  const int l    = tid & 63;
  const int row  = l & 15;
  const int kq   = l >> 4;
  const int r0   = blockIdx.x * 64 + wave * 16;

  {
    const int r = tid & 127, hf = tid >> 7;
    const __half* src = woT + (size_t)r * ND + hf * 64;
    _Float16* dst = &ws[r][hf * 64];
#pragma unroll
    for (int ch = 0; ch < 8; ++ch)
      *(f16x8*)(dst + ch * 8) = *(const f16x8*)(src + ch * 8);
  }

  f16x8 a[4];
#pragma unroll
  for (int s = 0; s < 4; ++s)
    a[s] = *(const f16x8*)(mh + (size_t)(r0 + row) * ND + s * 32 + kq * 8);

  __syncthreads();

  const int rb = r0 + kq * 4;
#pragma unroll 2
  for (int nt = 0; nt < 8; ++nt) {
    f32x4 c = {0.f, 0.f, 0.f, 0.f};
#pragma unroll
    for (int s = 0; s < 4; ++s) {
      const f16x8 b = *(const f16x8*)&ws[nt * 16 + row][s * 32 + kq * 8];
      c = __builtin_amdgcn_mfma_f32_16x16x32_f16(a[s], b, c, 0, 0, 0);
    }
    const int col = nt * 16 + row;
    const float bb = bo[col];
#pragma unroll
    for (int i = 0; i < 4; ++i)
      out[(size_t)(rb + i) * ND + col] = c[i] + bb;
  }
}

// ---------------- fused gather: R17 topology + one-chunk-deep K/V ping-pong ---
// 8 nodes/block, 32 lanes/node, chunk = 8 edges. K/V for chunk t+1 issued
// during chunk t's compute (addresses from pn, already resident). kz/vz kept
// as raw f16 pairs in float2 (2 VGPR each); A/B sets via 2x-unrolled body.
#define KVLOAD(SET, PP) do {                                                   \
  _Pragma("unroll")                                                            \
  for (int c = 0; c < 8; ++c) {                                                \
    const int col = __shfl((PP).x, c, 32);                                     \
    kz##SET[c] = *(const float2*)(K16 + (size_t)col * ND + hq);                \
    vz##SET[c] = *(const float2*)(V16 + (size_t)col * ND + hq);                \
  }                                                                            \
} while (0)

#define GBODY(CUR, NXT) do {                                                   \
  { /* ds_write ea(t) */                                                       \
    float* d = &eas[g][se * ED] + sp * 4;                                      \
    *(float4*)(d + 0)  = er0; *(float4*)(d + 16) = er1;                        \
    *(float4*)(d + 32) = er2; *(float4*)(d + 48) = er3;                        \
  }                                                                            \
  int2 pf = pn;                                                                \
  if (jp + 8 < j1) {                                                           \
    const int eidN = __shfl(pn.y, se, 32);                                     \
    const float4* s4 = (const float4*)(ea + (size_t)eidN * ED) + sp;           \
    er0 = s4[0]; er1 = s4[4]; er2 = s4[8]; er3 = s4[12];                       \
    pf = pair[min(jp + 16 + l8, jlast)];                                       \
    KVLOAD(NXT, pn);                                                           \
  }                                                                            \
  asm volatile("s_waitcnt lgkmcnt(0)" ::: "memory");                           \
  __builtin_amdgcn_sched_barrier(0);                                           \
  __builtin_amdgcn_s_setprio(1);                                               \
  _Pragma("unroll")                                                            \
  for (int c = 0; c < 8; ++c) {                                                \
    const __half2* kh = (const __half2*)&kz##CUR[c];                           \
    const float2 ka = __half22float2(kh[0]);                                   \
    const float2 kb = __half22float2(kh[1]);                                   \
    float s = ka.x * qv.x;                                                     \
    s = fmaf(qv.y, ka.y, s); s = fmaf(qv.z, kb.x, s); s = fmaf(qv.w, kb.y, s); \
    const float4* ep = (const float4*)&eas[g][c * ED + q * 16];                \
    _Pragma("unroll")                                                          \
    for (int i = 0; i < 4; ++i) {                                              \
      float4 a = ep[i];                                                        \
      s = fmaf(a.x, gg[4 * i + 0], s); s = fmaf(a.y, gg[4 * i + 1], s);        \
      s = fmaf(a.z, gg[4 * i + 2], s); s = fmaf(a.w, gg[4 * i + 3], s);        \
    }                                                                          \
    s += __shfl_xor(s, 1); s += __shfl_xor(s, 2);                              \
    const float es = (jp + c < j1) ? __expf(s + sb) : 0.f;                     \
    den += es;                                                                 \
    const __half2* vh = (const __half2*)&vz##CUR[c];                           \
    const float2 va = __half22float2(vh[0]);                                   \
    const float2 vb = __half22float2(vh[1]);                                   \
    acc.x = fmaf(es, va.x, acc.x); acc.y = fmaf(es, va.y, acc.y);              \
    acc.z = fmaf(es, vb.x, acc.z); acc.w = fmaf(es, vb.y, acc.w);              \
  }                                                                            \
  __builtin_amdgcn_s_setprio(0);                                               \
  p = pn; pn = pf; jp += 8;                                                    \
} while (0)

__global__ __launch_bounds__(256) void k_gather(const __half* __restrict__ qh,
                                                const __half* __restrict__ K16,
                                                const __half* __restrict__ V16,
                                                const float* __restrict__ ea,
                                                const int* __restrict__ off,
                                                const int2* __restrict__ pair,
                                                const __half* __restrict__ G16,
                                                const float* __restrict__ SB,
                                                __half* __restrict__ mh) {
  __shared__ float eas[8][8 * ED];   // 16 KB/block
  const int g = threadIdx.x >> 5;
  const int n = blockIdx.x * 8 + g;
  const int l = threadIdx.x & 31;
  const int h = l >> 2;
  const int q = l & 3;

  float gg[16];
  float4 qv;
  {
    const __half2* qp2 = (const __half2*)(qh + (size_t)n * ND + h * DK + q * 4);
    float2 q01 = __half22float2(qp2[0]);
    float2 q23 = __half22float2(qp2[1]);
    qv.x = q01.x * 0.25f; qv.y = q01.y * 0.25f;
    qv.z = q23.x * 0.25f; qv.w = q23.y * 0.25f;
  }
  const float sb = SB[n * NH + h];   // already x0.25
  {
    const float4* gp = (const float4*)(G16 + (size_t)n * 512 + h * 64 + q * 16);
    float4 c0 = gp[0], c1 = gp[1];
    const __half2* h0 = (const __half2*)&c0;
    const __half2* h1 = (const __half2*)&c1;
#pragma unroll
    for (int i = 0; i < 4; ++i) {
      float2 f0 = __half22float2(h0[i]);
      gg[2 * i + 0] = f0.x; gg[2 * i + 1] = f0.y;
      float2 f1 = __half22float2(h1[i]);
      gg[8 + 2 * i + 0] = f1.x; gg[8 + 2 * i + 1] = f1.y;
    }
  }

  float4 acc = make_float4(0.f, 0.f, 0.f, 0.f);
  float den = 0.f;

  const int j0 = off[n], j1 = off[n + 1];
  const int jlast = j1 - 1;
  const int hq = h * DK + q * 4;
  const int l8 = l & 7;
  const int se = l >> 2;   // staging edge 0..7
  const int sp = l & 3;    // staging float4-part

  if (j0 < j1) {
    int2 p = pair[min(j0 + l8, jlast)];
    float4 er0, er1, er2, er3;
    {
      const int eid = __shfl(p.y, se, 32);
      const float4* s4 = (const float4*)(ea + (size_t)eid * ED) + sp;
      er0 = s4[0]; er1 = s4[4]; er2 = s4[8]; er3 = s4[12];
    }
    int2 pn = pair[min(j0 + 8 + l8, jlast)];

    float2 kzA[8], vzA[8], kzB[8], vzB[8];
    KVLOAD(A, p);

    int jp = j0;
    while (jp < j1) {
      GBODY(A, B);
      if (jp < j1) GBODY(B, A);
    }
  }

  const float inv = 1.f / (den + 1e-8f);
  union { __half2 h2[2]; float2 f; } u;
  u.h2[0] = __floats2half2_rn(acc.x * inv, acc.y * inv);
  u.h2[1] = __floats2half2_rn(acc.z * inv, acc.w * inv);
  *(float2*)(mh + (size_t)n * ND + h * DK + q * 4) = u.f;
}

extern "C" void kernel_launch(void* const* d_in, const int* in_sizes, int n_in,
                              void* d_out, int out_size, void* d_ws, size_t ws_size,
                              hipStream_t stream) {
  const float* nodes = (const float*)d_in[0];
  const int*   ei    = (const int*)d_in[1];
  const float* ea    = (const float*)d_in[2];
  const float* wq    = (const float*)d_in[3];
  const float* bq    = (const float*)d_in[4];
  const float* wk    = (const float*)d_in[5];
  const float* bk    = (const float*)d_in[6];
  const float* wv    = (const float*)d_in[7];
  const float* bv    = (const float*)d_in[8];
  const float* we    = (const float*)d_in[9];
  const float* be    = (const float*)d_in[10];
  const float* wo    = (const float*)d_in[11];
  const float* bo    = (const float*)d_in[12];
  float* out = (float*)d_out;

  const size_t NND = (size_t)NN * ND;
  __half* qh   = (__half*)d_ws;              // NND
  __half* K16  = qh + NND;                   // NND
  __half* V16  = K16 + NND;                  // NND
  __half* mh   = V16 + NND;                  // NND
  __half* G16  = mh + NND;                   // NN*512
  __half* WT   = G16 + (size_t)NN * 512;     // 912*128
  __half* woT  = WT + (size_t)NWT * ND;      // 128*128
  float* SB    = (float*)(woT + ND * ND);    // NN*8
  float* bias_all = SB + (size_t)NN * NH;    // NWT
  int* hist    = (int*)(bias_all + NWT);     // NN
  int* pub     = hist + NN;                  // 160 (zeroed with hist)
  int* off     = pub + 160;                  // 40004
  int* cursor  = off + 40004;                // NN
  int2* pair   = (int2*)(cursor + NN);       // NE

  hipMemsetAsync(hist, 0, (NN + 160) * sizeof(int), stream);

  dim3 blk(256);

  k_prep_hist<<<dim3(PREP_NBLK + (NE + 255) / 256), blk, 0, stream>>>(
      wq, bq, wk, bk, wv, bv, we, be, wo, ei, WT, woT, bias_all, hist);

  k_scan_fused<<<dim3(SCAN_NBLK), blk, 0, stream>>>(hist, off, cursor, pub);

  k_gemm1_scatter<<<dim3(GEMM1_NBLK + (NE + 255) / 256), blk, 0, stream>>>(
      nodes, WT, bias_all, ei, cursor, pair, qh, K16, V16, G16, SB);

  k_gather<<<dim3(NN / 8), blk, 0, stream>>>(qh, K16, V16, ea, off, pair, G16, SB, mh);

  k_gemm2<<<dim3(NN / 64), blk, 0, stream>>>(mh, woT, bo, out);
}

// Round 20
// 184.070 us; speedup vs baseline: 1.0280x; 1.0280x over previous
//
#include <hip/hip_runtime.h>
#include <hip/hip_fp16.h>

#define NN  40000
#define NE  640000
#define ND  128
#define ED  64
#define NH  8
#define DK  16
#define NWT 912   // 384 (q|k|v) + 512 (G composed) + 16 (SB rows, 8 used)

#define SCAN_NBLK 157   // ceil(40000/256)
#define PREP_NBLK 524   // ceil((NWT*ND + ND*ND + NWT)/256)
#define GEMM1_NBLK 625  // NN/64

typedef _Float16 f16x8 __attribute__((ext_vector_type(8)));
typedef float    f32x4 __attribute__((ext_vector_type(4)));

// ---- prep (WT/woT/bias compose) + hist, merged into one launch ----
__global__ __launch_bounds__(256) void k_prep_hist(const float* __restrict__ wq,
                                                   const float* __restrict__ bq,
                                                   const float* __restrict__ wk,
                                                   const float* __restrict__ bk,
                                                   const float* __restrict__ wv,
                                                   const float* __restrict__ bv,
                                                   const float* __restrict__ we,
                                                   const float* __restrict__ be,
                                                   const float* __restrict__ wo,
                                                   const int* __restrict__ ei,
                                                   __half* __restrict__ WT,
                                                   __half* __restrict__ woT,
                                                   float* __restrict__ bias_all,
                                                   int* __restrict__ hist) {
  if (blockIdx.x >= PREP_NBLK) {
    const int e = (blockIdx.x - PREP_NBLK) * 256 + threadIdx.x;
    if (e < NE) atomicAdd(&hist[ei[e]], 1);
    return;
  }
  int idx = blockIdx.x * 256 + threadIdx.x;
  if (idx < NWT * ND) {
    const int n = idx >> 7, k = idx & 127;
    float v;
    if (n < 128)      v = wq[k * ND + n];
    else if (n < 256) v = wk[k * ND + (n - 128)];
    else if (n < 384) v = wv[k * ND + (n - 256)];
    else if (n < 896) {
      const int col = n - 384, h = col >> 6, j = col & 63;
      const float4* a = (const float4*)(wq + (size_t)k * ND + h * DK);
      const float4* b = (const float4*)(we + (size_t)j * ND + h * DK);
      float s = 0.f;
#pragma unroll
      for (int i = 0; i < 4; ++i) {
        float4 av = a[i], bv4 = b[i];
        s = fmaf(av.x, bv4.x, s); s = fmaf(av.y, bv4.y, s);
        s = fmaf(av.z, bv4.z, s); s = fmaf(av.w, bv4.w, s);
      }
      v = 0.25f * s;
    } else if (n < 904) {
      const int h = n - 896;
      const float4* a = (const float4*)(wq + (size_t)k * ND + h * DK);
      const float4* b = (const float4*)(be + h * DK);
      float s = 0.f;
#pragma unroll
      for (int i = 0; i < 4; ++i) {
        float4 av = a[i], bv4 = b[i];
        s = fmaf(av.x, bv4.x, s); s = fmaf(av.y, bv4.y, s);
        s = fmaf(av.z, bv4.z, s); s = fmaf(av.w, bv4.w, s);
      }
      v = 0.25f * s;
    } else v = 0.f;
    WT[idx] = __float2half_rn(v);
    return;
  }
  idx -= NWT * ND;
  if (idx < ND * ND) {
    const int n = idx >> 7, k = idx & 127;
    woT[idx] = __float2half_rn(wo[k * ND + n]);
    return;
  }
  idx -= ND * ND;
  if (idx < NWT) {
    float v;
    if (idx < 128)      v = bq[idx];
    else if (idx < 256) v = bk[idx - 128];
    else if (idx < 384) v = bv[idx - 256];
    else if (idx < 896) {
      const int col = idx - 384, h = col >> 6, j = col & 63;
      const float4* a = (const float4*)(bq + h * DK);
      const float4* b = (const float4*)(we + (size_t)j * ND + h * DK);
      float s = 0.f;
#pragma unroll
      for (int i = 0; i < 4; ++i) {
        float4 av = a[i], bv4 = b[i];
        s = fmaf(av.x, bv4.x, s); s = fmaf(av.y, bv4.y, s);
        s = fmaf(av.z, bv4.z, s); s = fmaf(av.w, bv4.w, s);
      }
      v = 0.25f * s;
    } else if (idx < 904) {
      const int h = idx - 896;
      const float4* a = (const float4*)(bq + h * DK);
      const float4* b = (const float4*)(be + h * DK);
      float s = 0.f;
#pragma unroll
      for (int i = 0; i < 4; ++i) {
        float4 av = a[i], bv4 = b[i];
        s = fmaf(av.x, bv4.x, s); s = fmaf(av.y, bv4.y, s);
        s = fmaf(av.z, bv4.z, s); s = fmaf(av.w, bv4.w, s);
      }
      v = 0.25f * s;
    } else v = 0.f;
    bias_all[idx] = v;
  }
}

// ---- single-kernel CSR scan: local scan + decoupled lookback --------------
__global__ __launch_bounds__(256) void k_scan_fused(const int* __restrict__ hist,
                                                    int* __restrict__ off,
                                                    int* __restrict__ cursor,
                                                    int* __restrict__ pub) {
  __shared__ int sh[256];
  const int tid = threadIdx.x;
  const int b = blockIdx.x;
  const int idx = b * 256 + tid;
  const int v = (idx < NN) ? hist[idx] : 0;
  sh[tid] = v;
  __syncthreads();
#pragma unroll
  for (int d = 1; d < 256; d <<= 1) {
    int t = (tid >= d) ? sh[tid - d] : 0;
    __syncthreads();
    sh[tid] += t;
    __syncthreads();
  }
  const int incl = sh[tid];
  const int total = sh[255];

  if (tid == 0) atomicExch(&pub[b], total + 1);

  int contrib = 0;
  if (tid < b) {
    int vv;
    do { vv = atomicAdd(&pub[tid], 0); } while (vv == 0);
    contrib = vv - 1;
  }
  __syncthreads();
  sh[tid] = contrib;
  __syncthreads();
#pragma unroll
  for (int d = 128; d > 0; d >>= 1) {
    if (tid < d) sh[tid] += sh[tid + d];
    __syncthreads();
  }
  const int excl = incl - v + sh[0];
  if (idx < NN) {
    off[idx] = excl;
    cursor[idx] = excl;
  }
  if (b == 0 && tid == 0) off[NN] = NE;
}

// ---- fused: MFMA GEMM 1 (blocks 0..624) + CSR scatter (blocks 625..) ----
__global__ __launch_bounds__(256) void k_gemm1_scatter(const float* __restrict__ x,
                                                       const __half* __restrict__ WT,
                                                       const float* __restrict__ bias_all,
                                                       const int* __restrict__ ei,
                                                       int* __restrict__ cursor,
                                                       int2* __restrict__ pair,
                                                       __half* __restrict__ qh,
                                                       __half* __restrict__ K16,
                                                       __half* __restrict__ V16,
                                                       __half* __restrict__ G16,
                                                       float* __restrict__ SB) {
  __shared__ _Float16 bs[4][16][132];

  if (blockIdx.x >= GEMM1_NBLK) {
    const int e = (blockIdx.x - GEMM1_NBLK) * 256 + threadIdx.x;
    if (e < NE) {
      const int row = ei[e];
      const int col = ei[NE + e];
      const int pos = atomicAdd(&cursor[row], 1);
      pair[pos] = make_int2(col, e);
    }
    return;
  }

  const int wave = threadIdx.x >> 6;
  const int l    = threadIdx.x & 63;
  const int row  = l & 15;
  const int kq   = l >> 4;
  const int r0   = blockIdx.x * 64 + wave * 16;

  f16x8 a[4];
#pragma unroll
  for (int s = 0; s < 4; ++s) {
    const float4* ap = (const float4*)(x + (size_t)(r0 + row) * ND + s * 32 + kq * 8);
    const float4 f0 = ap[0], f1 = ap[1];
    f16x8 t;
    t[0] = (_Float16)f0.x; t[1] = (_Float16)f0.y; t[2] = (_Float16)f0.z; t[3] = (_Float16)f0.w;
    t[4] = (_Float16)f1.x; t[5] = (_Float16)f1.y; t[6] = (_Float16)f1.z; t[7] = (_Float16)f1.w;
    a[s] = t;
  }

  const int rb = r0 + kq * 4;

  for (int nc = 0; nc < 56; nc += 4) {
    __syncthreads();
    {
      const __half* src = WT + (size_t)((nc + wave) * 16 + row) * ND;
      _Float16* dst = &bs[wave][row][0];
#pragma unroll
      for (int ch = 0; ch < 4; ++ch) {
        const int o = (kq + ch * 4) * 8;
        *(f16x8*)(dst + o) = *(const f16x8*)(src + o);
      }
    }
    __syncthreads();
#pragma unroll
    for (int t = 0; t < 4; ++t) {
      const int nt = nc + t;
      f32x4 c = {0.f, 0.f, 0.f, 0.f};
#pragma unroll
      for (int s = 0; s < 4; ++s) {
        const f16x8 b = *(const f16x8*)&bs[t][row][s * 32 + kq * 8];
        c = __builtin_amdgcn_mfma_f32_16x16x32_f16(a[s], b, c, 0, 0, 0);
      }
      const int col = nt * 16 + row;
      const float bb = bias_all[col];
      if (nt < 24) {
        __half* dst = (nt < 8) ? (qh + col) : (nt < 16) ? (K16 + (col - 128)) : (V16 + (col - 256));
#pragma unroll
        for (int i = 0; i < 4; ++i)
          dst[(size_t)(rb + i) * ND] = __float2half_rn(c[i] + bb);
      } else {
        const int gcol = col - 384;
#pragma unroll
        for (int i = 0; i < 4; ++i)
          G16[(size_t)(rb + i) * 512 + gcol] = __float2half_rn(c[i] + bb);
      }
    }
  }

  {
    f32x4 c = {0.f, 0.f, 0.f, 0.f};
#pragma unroll
    for (int s = 0; s < 4; ++s) {
      const f16x8 b = *(const f16x8*)(WT + (size_t)(896 + row) * ND + s * 32 + kq * 8);
      c = __builtin_amdgcn_mfma_f32_16x16x32_f16(a[s], b, c, 0, 0, 0);
    }
    if (row < 8) {
      const float bb = bias_all[896 + row];
#pragma unroll
      for (int i = 0; i < 4; ++i)
        SB[(size_t)(rb + i) * NH + row] = c[i] + bb;
    }
  }
}

// ---- MFMA GEMM 2: mh(f16) @ woT^T + bo -> out(f32); woT fully LDS-staged ----
__global__ __launch_bounds__(256) void k_gemm2(const __half* __restrict__ mh,
                                               const __half* __restrict__ woT,
                                               const float* __restrict__ bo,
                                               float* __restrict__ out) {
  __shared__ _Float16 ws[128][132];
  const int tid  = threadIdx.x;
  const int wave = tid >> 6;
  const int l    = tid & 63;
  const int row  = l & 15;
  const int kq   = l >> 4;
  const int r0   = blockIdx.x * 64 + wave * 16;

  {
    const int r = tid & 127, hf = tid >> 7;
    const __half* src = woT + (size_t)r * ND + hf * 64;
    _Float16* dst = &ws[r][hf * 64];
#pragma unroll
    for (int ch = 0; ch < 8; ++ch)
      *(f16x8*)(dst + ch * 8) = *(const f16x8*)(src + ch * 8);
  }

  f16x8 a[4];
#pragma unroll
  for (int s = 0; s < 4; ++s)
    a[s] = *(const f16x8*)(mh + (size_t)(r0 + row) * ND + s * 32 + kq * 8);

  __syncthreads();

  const int rb = r0 + kq * 4;
#pragma unroll 2
  for (int nt = 0; nt < 8; ++nt) {
    f32x4 c = {0.f, 0.f, 0.f, 0.f};
#pragma unroll
    for (int s = 0; s < 4; ++s) {
      const f16x8 b = *(const f16x8*)&ws[nt * 16 + row][s * 32 + kq * 8];
      c = __builtin_amdgcn_mfma_f32_16x16x32_f16(a[s], b, c, 0, 0, 0);
    }
    const int col = nt * 16 + row;
    const float bb = bo[col];
#pragma unroll
    for (int i = 0; i < 4; ++i)
      out[(size_t)(rb + i) * ND + col] = c[i] + bb;
  }
}

// ---------------- fused gather (R18 version: within-chunk K/V hoist + setprio)
__global__ __launch_bounds__(256) void k_gather(const __half* __restrict__ qh,
                                                const __half* __restrict__ K16,
                                                const __half* __restrict__ V16,
                                                const float* __restrict__ ea,
                                                const int* __restrict__ off,
                                                const int2* __restrict__ pair,
                                                const __half* __restrict__ G16,
                                                const float* __restrict__ SB,
                                                __half* __restrict__ mh) {
  __shared__ float eas[8][8 * ED];   // 16 KB/block
  const int g = threadIdx.x >> 5;
  const int n = blockIdx.x * 8 + g;
  const int l = threadIdx.x & 31;
  const int h = l >> 2;
  const int q = l & 3;

  float gg[16];
  float4 qv;
  {
    const __half2* qp2 = (const __half2*)(qh + (size_t)n * ND + h * DK + q * 4);
    float2 q01 = __half22float2(qp2[0]);
    float2 q23 = __half22float2(qp2[1]);
    qv.x = q01.x * 0.25f; qv.y = q01.y * 0.25f;
    qv.z = q23.x * 0.25f; qv.w = q23.y * 0.25f;
  }
  const float sb = SB[n * NH + h];   // already x0.25
  {
    const float4* gp = (const float4*)(G16 + (size_t)n * 512 + h * 64 + q * 16);
    float4 c0 = gp[0], c1 = gp[1];
    const __half2* h0 = (const __half2*)&c0;
    const __half2* h1 = (const __half2*)&c1;
#pragma unroll
    for (int i = 0; i < 4; ++i) {
      float2 f0 = __half22float2(h0[i]);
      gg[2 * i + 0] = f0.x; gg[2 * i + 1] = f0.y;
      float2 f1 = __half22float2(h1[i]);
      gg[8 + 2 * i + 0] = f1.x; gg[8 + 2 * i + 1] = f1.y;
    }
  }

  float4 acc = make_float4(0.f, 0.f, 0.f, 0.f);
  float den = 0.f;

  const int j0 = off[n], j1 = off[n + 1];
  const int jlast = j1 - 1;
  const int hq = h * DK + q * 4;
  const int l8 = l & 7;
  const int se = l >> 2;   // staging edge 0..7
  const int sp = l & 3;    // staging float4-part

  if (j0 < j1) {
    int2 p = pair[min(j0 + l8, jlast)];
    float4 er0, er1, er2, er3;
    {
      const int eid = __shfl(p.y, se, 32);
      const float4* s4 = (const float4*)(ea + (size_t)eid * ED) + sp;
      er0 = s4[0]; er1 = s4[4]; er2 = s4[8]; er3 = s4[12];
    }
    int2 pn = pair[min(j0 + 8 + l8, jlast)];

    for (int jp = j0; jp < j1; jp += 8) {
      // 1. extract cols and issue ALL chunk K/V loads up-front
      int cols[8];
#pragma unroll
      for (int c = 0; c < 8; ++c) cols[c] = __shfl(p.x, c, 32);
      float2 kz[8], vz[8];
#pragma unroll
      for (int c = 0; c < 8; ++c) {
        kz[c] = *(const float2*)(K16 + (size_t)cols[c] * ND + hq);
        vz[c] = *(const float2*)(V16 + (size_t)cols[c] * ND + hq);
      }

      // 2. ds_write ea(t)
      {
        float* d = &eas[g][se * ED] + sp * 4;
        *(float4*)(d + 0)  = er0; *(float4*)(d + 16) = er1;
        *(float4*)(d + 32) = er2; *(float4*)(d + 48) = er3;
      }
      // prefetch ea(t+1) regs + pair(t+2)
      int2 pf = pn;
      if (jp + 8 < j1) {
        const int eidN = __shfl(pn.y, se, 32);
        const float4* s4 = (const float4*)(ea + (size_t)eidN * ED) + sp;
        er0 = s4[0]; er1 = s4[4]; er2 = s4[8]; er3 = s4[12];
        pf = pair[min(jp + 16 + l8, jlast)];
      }

      // 3. staging visible to the 32-group
      asm volatile("s_waitcnt lgkmcnt(0)" ::: "memory");
      __builtin_amdgcn_sched_barrier(0);

      // compute 8 edges from preloaded kz/vz + LDS ea (prio-boosted)
      __builtin_amdgcn_s_setprio(1);
#pragma unroll
      for (int c = 0; c < 8; ++c) {
        const __half2* kh = (const __half2*)&kz[c];
        const float2 ka = __half22float2(kh[0]);
        const float2 kb = __half22float2(kh[1]);

        float s = ka.x * qv.x;
        s = fmaf(qv.y, ka.y, s); s = fmaf(qv.z, kb.x, s); s = fmaf(qv.w, kb.y, s);

        const float4* ep = (const float4*)&eas[g][c * ED + q * 16];
#pragma unroll
        for (int i = 0; i < 4; ++i) {
          float4 a = ep[i];
          s = fmaf(a.x, gg[4 * i + 0], s); s = fmaf(a.y, gg[4 * i + 1], s);
          s = fmaf(a.z, gg[4 * i + 2], s); s = fmaf(a.w, gg[4 * i + 3], s);
        }

        s += __shfl_xor(s, 1); s += __shfl_xor(s, 2);
        const float es = (jp + c < j1) ? __expf(s + sb) : 0.f;
        den += es;

        const __half2* vh = (const __half2*)&vz[c];
        const float2 va = __half22float2(vh[0]);
        const float2 vb = __half22float2(vh[1]);
        acc.x = fmaf(es, va.x, acc.x); acc.y = fmaf(es, va.y, acc.y);
        acc.z = fmaf(es, vb.x, acc.z); acc.w = fmaf(es, vb.y, acc.w);
      }
      __builtin_amdgcn_s_setprio(0);

      p = pn; pn = pf;
    }
  }

  const float inv = 1.f / (den + 1e-8f);
  union { __half2 h2[2]; float2 f; } u;
  u.h2[0] = __floats2half2_rn(acc.x * inv, acc.y * inv);
  u.h2[1] = __floats2half2_rn(acc.z * inv, acc.w * inv);
  *(float2*)(mh + (size_t)n * ND + h * DK + q * 4) = u.f;
}

extern "C" void kernel_launch(void* const* d_in, const int* in_sizes, int n_in,
                              void* d_out, int out_size, void* d_ws, size_t ws_size,
                              hipStream_t stream) {
  const float* nodes = (const float*)d_in[0];
  const int*   ei    = (const int*)d_in[1];
  const float* ea    = (const float*)d_in[2];
  const float* wq    = (const float*)d_in[3];
  const float* bq    = (const float*)d_in[4];
  const float* wk    = (const float*)d_in[5];
  const float* bk    = (const float*)d_in[6];
  const float* wv    = (const float*)d_in[7];
  const float* bv    = (const float*)d_in[8];
  const float* we    = (const float*)d_in[9];
  const float* be    = (const float*)d_in[10];
  const float* wo    = (const float*)d_in[11];
  const float* bo    = (const float*)d_in[12];
  float* out = (float*)d_out;

  const size_t NND = (size_t)NN * ND;
  __half* qh   = (__half*)d_ws;              // NND
  __half* K16  = qh + NND;                   // NND
  __half* V16  = K16 + NND;                  // NND
  __half* mh   = V16 + NND;                  // NND
  __half* G16  = mh + NND;                   // NN*512
  __half* WT   = G16 + (size_t)NN * 512;     // 912*128
  __half* woT  = WT + (size_t)NWT * ND;      // 128*128
  float* SB    = (float*)(woT + ND * ND);    // NN*8
  float* bias_all = SB + (size_t)NN * NH;    // NWT
  int* hist    = (int*)(bias_all + NWT);     // NN
  int* pub     = hist + NN;                  // 160 (zeroed with hist)
  int* off     = pub + 160;                  // 40004
  int* cursor  = off + 40004;                // NN
  int2* pair   = (int2*)(cursor + NN);       // NE

  hipMemsetAsync(hist, 0, (NN + 160) * sizeof(int), stream);

  dim3 blk(256);

  k_prep_hist<<<dim3(PREP_NBLK + (NE + 255) / 256), blk, 0, stream>>>(
      wq, bq, wk, bk, wv, bv, we, be, wo, ei, WT, woT, bias_all, hist);

  k_scan_fused<<<dim3(SCAN_NBLK), blk, 0, stream>>>(hist, off, cursor, pub);

  k_gemm1_scatter<<<dim3(GEMM1_NBLK + (NE + 255) / 256), blk, 0, stream>>>(
      nodes, WT, bias_all, ei, cursor, pair, qh, K16, V16, G16, SB);

  k_gather<<<dim3(NN / 8), blk, 0, stream>>>(qh, K16, V16, ea, off, pair, G16, SB, mh);

  k_gemm2<<<dim3(NN / 64), blk, 0, stream>>>(mh, woT, bo, out);
}